// Round 13
// baseline (462.633 us; speedup 1.0000x reference)
//
#include <hip/hip_runtime.h>
#include <hip/hip_cooperative_groups.h>

namespace cg = cooperative_groups;

typedef __bf16 bf16_t;
typedef bf16_t bf16x8 __attribute__((ext_vector_type(8)));
typedef bf16_t bf16x4 __attribute__((ext_vector_type(4)));
typedef float f32x4 __attribute__((ext_vector_type(4)));

// load 8 contiguous elements as bf16x8 (fp32 source converts in-register)
__device__ inline bf16x8 ld8(const float* p) {
    f32x4 a = *reinterpret_cast<const f32x4*>(p);
    f32x4 b = *reinterpret_cast<const f32x4*>(p + 4);
    bf16x8 r = { (bf16_t)a[0], (bf16_t)a[1], (bf16_t)a[2], (bf16_t)a[3],
                 (bf16_t)b[0], (bf16_t)b[1], (bf16_t)b[2], (bf16_t)b[3] };
    return r;
}
__device__ inline bf16x8 ld8(const bf16_t* p) {
    return *reinterpret_cast<const bf16x8*>(p);
}

// ---------------- GEMM phase: C = A * B^T (+bias), 64x64 tile, BK=64, pipelined. LDS 18432B ----------------
template <typename AT, typename BT, typename OUT_T, bool HAS_BIAS>
__device__ inline void gemm_phase(char* smem, int l, int numTiles, int tid,
    const AT* __restrict__ A, const BT* __restrict__ B,
    OUT_T* __restrict__ C, const float* __restrict__ bias,
    int K, int lda, int ldb, int ldc)
{
    bf16_t (*As)[72] = reinterpret_cast<bf16_t(*)[72]>(smem);          // 64x72
    bf16_t (*Bs)[72] = reinterpret_cast<bf16_t(*)[72]>(smem + 9216);   // 64x72

    const int lp = (l & 7) * (numTiles >> 3) + (l >> 3);   // bijective XCD chunking
    const int m0 = (lp & 7) * 64;                          // 8 m-tiles (M=512)
    const int n0 = (lp >> 3) * 64;

    const int lane = tid & 63;
    const int wave = tid >> 6;
    const int srow = tid >> 3;          // 0..31 (second chunk: +32)
    const int soff = (tid & 7) * 8;     // 0,8,..,56

    bf16x8 rA0, rA1, rB0, rB1;
    rA0 = ld8(&A[(long)(m0 + srow)      * lda + soff]);
    rA1 = ld8(&A[(long)(m0 + srow + 32) * lda + soff]);
    rB0 = ld8(&B[(long)(n0 + srow)      * ldb + soff]);
    rB1 = ld8(&B[(long)(n0 + srow + 32) * ldb + soff]);

    f32x4 acc[4] = {};

    for (int k0 = 0; k0 < K; k0 += 64) {
        __syncthreads();   // protect As/Bs reuse across iterations / phases
        *reinterpret_cast<bf16x8*>(&As[srow][soff])      = rA0;
        *reinterpret_cast<bf16x8*>(&As[srow + 32][soff]) = rA1;
        *reinterpret_cast<bf16x8*>(&Bs[srow][soff])      = rB0;
        *reinterpret_cast<bf16x8*>(&Bs[srow + 32][soff]) = rB1;
        __syncthreads();

        if (k0 + 64 < K) {              // issue next-tile loads; consumed after next barrier
            rA0 = ld8(&A[(long)(m0 + srow)      * lda + k0 + 64 + soff]);
            rA1 = ld8(&A[(long)(m0 + srow + 32) * lda + k0 + 64 + soff]);
            rB0 = ld8(&B[(long)(n0 + srow)      * ldb + k0 + 64 + soff]);
            rB1 = ld8(&B[(long)(n0 + srow + 32) * ldb + k0 + 64 + soff]);
        }

#pragma unroll
        for (int ks = 0; ks < 64; ks += 32) {
            bf16x8 af = *reinterpret_cast<const bf16x8*>(&As[wave * 16 + (lane & 15)][(lane >> 4) * 8 + ks]);
#pragma unroll
            for (int nf = 0; nf < 4; ++nf) {
                bf16x8 bfr = *reinterpret_cast<const bf16x8*>(&Bs[nf * 16 + (lane & 15)][(lane >> 4) * 8 + ks]);
                acc[nf] = __builtin_amdgcn_mfma_f32_16x16x32_bf16(af, bfr, acc[nf], 0, 0, 0);
            }
        }
    }
    __syncthreads();

    const int crow0 = m0 + wave * 16 + (lane >> 4) * 4;
    const int ccol0 = n0 + (lane & 15);
#pragma unroll
    for (int nf = 0; nf < 4; ++nf) {
        const int col = ccol0 + nf * 16;
        const float bv = HAS_BIAS ? bias[col] : 0.0f;
#pragma unroll
        for (int v = 0; v < 4; ++v) {
            C[(long)(crow0 + v) * ldc + col] = (OUT_T)(acc[nf][v] + bv);
        }
    }
}

// ---------------- qk_softmax phase, chunked-K (LDS 18432B): blk in [0,96) ----------------
__device__ inline void qk_phase(char* smem, int blk, int t,
    const bf16_t* __restrict__ qkv, bf16_t* __restrict__ probs)
{
    bf16_t (*Qs)[72] = reinterpret_cast<bf16_t(*)[72]>(smem);          // 64x72
    bf16_t (*Ks)[72] = reinterpret_cast<bf16_t(*)[72]>(smem + 9216);   // 64x72 (reused 4x)

    const int bh = blk % 24;
    const int m0 = (blk / 24) * 64;
    const int b = bh / 12, h = bh % 12;
    const bf16_t* qbase = qkv + (long)b * 589824 + h * 64;
    const bf16_t* kbase = qkv + (long)b * 589824 + 768 + h * 64;

    const int srow = t >> 3;           // 0..31
    const int soff = (t & 7) * 8;
    const int lane = t & 63, wave = t >> 6;

    f32x4 acc[16] = {};

    // stage Q once (barrier inside first chunk iteration covers it)
    __syncthreads();
    *reinterpret_cast<bf16x8*>(&Qs[srow][soff]) =
        *reinterpret_cast<const bf16x8*>(qbase + (long)(m0 + srow) * 2304 + soff);
    *reinterpret_cast<bf16x8*>(&Qs[srow + 32][soff]) =
        *reinterpret_cast<const bf16x8*>(qbase + (long)(m0 + srow + 32) * 2304 + soff);

#pragma unroll
    for (int nc = 0; nc < 4; ++nc) {
        if (nc) __syncthreads();       // protect Ks reuse
        *reinterpret_cast<bf16x8*>(&Ks[srow][soff]) =
            *reinterpret_cast<const bf16x8*>(kbase + (long)(nc * 64 + srow) * 2304 + soff);
        *reinterpret_cast<bf16x8*>(&Ks[srow + 32][soff]) =
            *reinterpret_cast<const bf16x8*>(kbase + (long)(nc * 64 + srow + 32) * 2304 + soff);
        __syncthreads();

#pragma unroll
        for (int ks = 0; ks < 64; ks += 32) {
            bf16x8 af = *reinterpret_cast<const bf16x8*>(&Qs[wave * 16 + (lane & 15)][(lane >> 4) * 8 + ks]);
#pragma unroll
            for (int nf = 0; nf < 4; ++nf) {
                bf16x8 bfr = *reinterpret_cast<const bf16x8*>(&Ks[nf * 16 + (lane & 15)][(lane >> 4) * 8 + ks]);
                acc[nc * 4 + nf] = __builtin_amdgcn_mfma_f32_16x16x32_bf16(af, bfr, acc[nc * 4 + nf], 0, 0, 0);
            }
        }
    }
    __syncthreads();

    // acc[i] holds col = i*16 + (lane&15): same layout as before
    float inv[4];
#pragma unroll
    for (int v = 0; v < 4; ++v) {
        float mm = -1e30f;
#pragma unroll
        for (int nf = 0; nf < 16; ++nf) { acc[nf][v] *= 0.125f; mm = fmaxf(mm, acc[nf][v]); }
#pragma unroll
        for (int o = 1; o < 16; o <<= 1) mm = fmaxf(mm, __shfl_xor(mm, o));
        float s = 0.0f;
#pragma unroll
        for (int nf = 0; nf < 16; ++nf) { float e = __expf(acc[nf][v] - mm); acc[nf][v] = e; s += e; }
#pragma unroll
        for (int o = 1; o < 16; o <<= 1) s += __shfl_xor(s, o);
        inv[v] = 1.0f / s;
    }

    bf16_t* prow = probs + ((long)bh * 256 + m0 + wave * 16 + (lane >> 4) * 4) * 256 + (lane & 15);
#pragma unroll
    for (int nf = 0; nf < 16; ++nf) {
#pragma unroll
        for (int v = 0; v < 4; ++v) {
            prow[(long)v * 256 + nf * 16] = (bf16_t)(acc[nf][v] * inv[v]);
        }
    }
}

// ---------------- attnd phase (LDS 7184B): unit u -> (bi = u&511, cc = u>>9) ----------------
__device__ inline void attnd_phase(char* smem, int u, int t,
    const bf16_t* __restrict__ attn, const bf16_t* __restrict__ qkv,
    const float* __restrict__ d, bf16_t* __restrict__ oh)
{
    float* attn_s = reinterpret_cast<float*>(smem);                     // 4*257 f32
    f32x4 (*partial)[64] = reinterpret_cast<f32x4(*)[64]>(smem + 4112); // 3x64 f32x4

    const int bi = u & 511;
    const int b  = bi >> 8;
    const int i  = bi & 255;
    const int cc = u >> 9;
    const int lane = t & 63, wave = t >> 6;

#pragma unroll
    for (int q = 0; q < 4; ++q) {
        attn_s[q * 257 + t] = (float)attn[(((long)(b * 12 + cc * 4 + q)) * 256 + i) * 256 + t];
    }
    __syncthreads();

    const int c0 = cc * 256 + lane * 4;
    const float* arow = attn_s + (lane >> 4) * 257;
    const int jb = wave * 64;
    const f32x4* dp = reinterpret_cast<const f32x4*>(d + (long)bi * 196608 + (long)jb * 768 + c0);
    const bf16_t* vp = qkv + (long)b * 589824 + (long)jb * 2304 + 1536 + c0;

    f32x4 acc = {};
#pragma unroll 8
    for (int jj = 0; jj < 64; ++jj) {
        f32x4 dv = __builtin_nontemporal_load(dp + (long)jj * 192);
        bf16x4 vv = *reinterpret_cast<const bf16x4*>(vp + (long)jj * 2304);
        float a = arow[jb + jj];
        acc[0] = fmaf(a, dv[0] + (float)vv[0], acc[0]);
        acc[1] = fmaf(a, dv[1] + (float)vv[1], acc[1]);
        acc[2] = fmaf(a, dv[2] + (float)vv[2], acc[2]);
        acc[3] = fmaf(a, dv[3] + (float)vv[3], acc[3]);
    }

    if (wave) partial[wave - 1][lane] = acc;
    __syncthreads();
    if (wave == 0) {
        acc += partial[0][lane] + partial[1][lane] + partial[2][lane];
        bf16x4 o = { (bf16_t)acc[0], (bf16_t)acc[1], (bf16_t)acc[2], (bf16_t)acc[3] };
        *reinterpret_cast<bf16x4*>(oh + (long)bi * 768 + c0) = o;
    }
}

// ---------------- cooperative mega-kernel (grid-stride phases; LDS 18432B -> 3 blocks/CU) ----------------
__global__ __launch_bounds__(256, 3) void mega(
    const float* __restrict__ x, const float* __restrict__ dg,
    const float* __restrict__ w_qkv, const float* __restrict__ w_proj,
    const float* __restrict__ b_proj, float* __restrict__ outg,
    bf16_t* __restrict__ qkvb, bf16_t* __restrict__ probs, bf16_t* __restrict__ oh)
{
    __shared__ __align__(16) char smem[18432];
    cg::grid_group grid = cg::this_grid();
    const int blk = blockIdx.x;
    const int nb  = gridDim.x;
    const int tid = threadIdx.x;

    // P1: qkv = x @ w_qkv^T  (288 tiles)
    for (int l = blk; l < 288; l += nb)
        gemm_phase<float, float, bf16_t, false>(smem, l, 288, tid,
            x, w_qkv, qkvb, nullptr, 768, 768, 768, 2304);
    __threadfence();
    grid.sync();

    // P2: probs = softmax((q/8) k^T) -> bf16  (96 tiles)
    for (int l = blk; l < 96; l += nb)
        qk_phase(smem, l, tid, qkvb, probs);
    __threadfence();
    grid.sync();

    // P3: oh = attn @ (v + d)  (1536 units)
    for (int u = blk; u < 1536; u += nb)
        attnd_phase(smem, u, tid, probs, qkvb, dg, oh);
    __threadfence();
    grid.sync();

    // P4: out = oh @ w_proj^T + b_proj  (96 tiles)
    for (int l = blk; l < 96; l += nb)
        gemm_phase<bf16_t, float, float, true>(smem, l, 96, tid,
            oh, w_proj, outg, b_proj, 768, 768, 768, 768);
}

// ---------------- fallback standalone kernels (round-9 proven path) ----------------
template <typename AT, typename BT, typename OUT_T, bool HAS_BIAS>
__global__ __launch_bounds__(256) void gemm_bt_k(
    const AT* __restrict__ A, const BT* __restrict__ B,
    OUT_T* __restrict__ C, const float* __restrict__ bias,
    int K, int lda, int ldb, int ldc)
{
    __shared__ __align__(16) char smem[18432];
    gemm_phase<AT, BT, OUT_T, HAS_BIAS>(smem, blockIdx.x, gridDim.x, threadIdx.x,
                                        A, B, C, bias, K, lda, ldb, ldc);
}

__global__ __launch_bounds__(256) void qk_softmax_k(
    const bf16_t* __restrict__ qkv, bf16_t* __restrict__ probs)
{
    __shared__ __align__(16) char smem[18432];
    qk_phase(smem, blockIdx.x, threadIdx.x, qkv, probs);
}

__global__ __launch_bounds__(256) void attnd_k(
    const bf16_t* __restrict__ attn, const bf16_t* __restrict__ qkv,
    const float* __restrict__ d, bf16_t* __restrict__ oh)
{
    __shared__ __align__(16) char smem[7184];
    attnd_phase(smem, blockIdx.x + (blockIdx.y << 9), threadIdx.x, attn, qkv, d, oh);
}

// ---------------- launch ----------------
extern "C" void kernel_launch(void* const* d_in, const int* in_sizes, int n_in,
                              void* d_out, int out_size, void* d_ws, size_t ws_size,
                              hipStream_t stream) {
    const float* x      = (const float*)d_in[0];   // [2,256,768]
    const float* d      = (const float*)d_in[1];   // [2,256,256,768]
    const float* w_qkv  = (const float*)d_in[2];   // [2304,768]
    const float* w_proj = (const float*)d_in[3];   // [768,768]
    const float* b_proj = (const float*)d_in[4];   // [768]
    float* out = (float*)d_out;                    // [2,256,768]

    char* ws = (char*)d_ws;
    bf16_t* qkvb  = (bf16_t*)(ws);                 //  512x2304 bf16
    bf16_t* probs = (bf16_t*)(ws + 2359296);       //  24x256x256 bf16
    bf16_t* oh    = (bf16_t*)(ws + 5505024);       //  512x768 bf16

    // deterministic grid sizing from occupancy (host-side query, capture-safe)
    int occ = 0;
    hipError_t qerr = hipOccupancyMaxActiveBlocksPerMultiprocessor(&occ, mega, 256, 0);
    if (qerr != hipSuccess) occ = 0;

    if (occ >= 2) {
        const int nb = 256 * (occ >= 3 ? 3 : 2);   // 768 or 512 blocks, all co-resident
        void* args[] = { (void*)&x, (void*)&d, (void*)&w_qkv, (void*)&w_proj,
                         (void*)&b_proj, (void*)&out, (void*)&qkvb, (void*)&probs, (void*)&oh };
        hipError_t lerr = hipLaunchCooperativeKernel((const void*)mega, dim3(nb), dim3(256),
                                                     args, 0, stream);
        if (lerr == hipSuccess) return;
    }

    // fallback: proven 4-kernel path (~99 us)
    gemm_bt_k<float, float, bf16_t, false><<<288, 256, 0, stream>>>(
        x, w_qkv, qkvb, nullptr, 768, 768, 768, 2304);
    qk_softmax_k<<<96, 256, 0, stream>>>(qkvb, probs);
    attnd_k<<<dim3(512, 3), 256, 0, stream>>>(probs, qkvb, d, oh);
    gemm_bt_k<bf16_t, float, float, true><<<96, 256, 0, stream>>>(
        oh, w_proj, out, b_proj, 768, 768, 768, 768);
}

// Round 14
// 115.764 us; speedup vs baseline: 3.9963x; 3.9963x over previous
//
#include <hip/hip_runtime.h>

typedef __bf16 bf16_t;
typedef bf16_t bf16x8 __attribute__((ext_vector_type(8)));
typedef bf16_t bf16x4 __attribute__((ext_vector_type(4)));
typedef float f32x4 __attribute__((ext_vector_type(4)));

// load 8 contiguous elements as bf16x8 (fp32 source converts in-register)
__device__ inline bf16x8 ld8(const float* p) {
    f32x4 a = *reinterpret_cast<const f32x4*>(p);
    f32x4 b = *reinterpret_cast<const f32x4*>(p + 4);
    bf16x8 r = { (bf16_t)a[0], (bf16_t)a[1], (bf16_t)a[2], (bf16_t)a[3],
                 (bf16_t)b[0], (bf16_t)b[1], (bf16_t)b[2], (bf16_t)b[3] };
    return r;
}
__device__ inline bf16x8 ld8(const bf16_t* p) {
    return *reinterpret_cast<const bf16x8*>(p);
}

// ---------------- GEMM: C = A * B^T (+bias); fp32/bf16 sources converted during staging ----------------
// 64x64 tile, BK=64, software-pipelined, XCD-aware 1-D grid remap.
template <typename AT, typename BT, typename OUT_T, bool HAS_BIAS>
__global__ __launch_bounds__(256) void gemm_bt(
    const AT* __restrict__ A, const BT* __restrict__ B,
    OUT_T* __restrict__ C, const float* __restrict__ bias,
    int K, int lda, int ldb, int ldc)
{
    const int l  = blockIdx.x;
    const int lp = (l & 7) * (gridDim.x >> 3) + (l >> 3);   // bijective XCD chunking (total%8==0)
    const int m0 = (lp & 7) * 64;                           // 8 m-tiles (M=512)
    const int n0 = (lp >> 3) * 64;

    __shared__ __align__(16) bf16_t As[64][72];   // +8 pad -> 2-way bank alias (free)
    __shared__ __align__(16) bf16_t Bs[64][72];

    const int tid  = threadIdx.x;
    const int lane = tid & 63;
    const int wave = tid >> 6;
    const int srow = tid >> 3;          // 0..31 (second chunk: +32)
    const int soff = (tid & 7) * 8;     // 0,8,..,56

    bf16x8 rA0, rA1, rB0, rB1;
    rA0 = ld8(&A[(long)(m0 + srow)      * lda + soff]);
    rA1 = ld8(&A[(long)(m0 + srow + 32) * lda + soff]);
    rB0 = ld8(&B[(long)(n0 + srow)      * ldb + soff]);
    rB1 = ld8(&B[(long)(n0 + srow + 32) * ldb + soff]);

    f32x4 acc[4] = {};

    for (int k0 = 0; k0 < K; k0 += 64) {
        *reinterpret_cast<bf16x8*>(&As[srow][soff])      = rA0;
        *reinterpret_cast<bf16x8*>(&As[srow + 32][soff]) = rA1;
        *reinterpret_cast<bf16x8*>(&Bs[srow][soff])      = rB0;
        *reinterpret_cast<bf16x8*>(&Bs[srow + 32][soff]) = rB1;
        __syncthreads();

        if (k0 + 64 < K) {              // issue next-tile loads; consumed after next barrier
            rA0 = ld8(&A[(long)(m0 + srow)      * lda + k0 + 64 + soff]);
            rA1 = ld8(&A[(long)(m0 + srow + 32) * lda + k0 + 64 + soff]);
            rB0 = ld8(&B[(long)(n0 + srow)      * ldb + k0 + 64 + soff]);
            rB1 = ld8(&B[(long)(n0 + srow + 32) * ldb + k0 + 64 + soff]);
        }

#pragma unroll
        for (int ks = 0; ks < 64; ks += 32) {
            bf16x8 af = *reinterpret_cast<const bf16x8*>(&As[wave * 16 + (lane & 15)][(lane >> 4) * 8 + ks]);
#pragma unroll
            for (int nf = 0; nf < 4; ++nf) {
                bf16x8 bfr = *reinterpret_cast<const bf16x8*>(&Bs[nf * 16 + (lane & 15)][(lane >> 4) * 8 + ks]);
                acc[nf] = __builtin_amdgcn_mfma_f32_16x16x32_bf16(af, bfr, acc[nf], 0, 0, 0);
            }
        }
        __syncthreads();
    }

    const int crow0 = m0 + wave * 16 + (lane >> 4) * 4;
    const int ccol0 = n0 + (lane & 15);
#pragma unroll
    for (int nf = 0; nf < 4; ++nf) {
        const int col = ccol0 + nf * 16;
        const float bv = HAS_BIAS ? bias[col] : 0.0f;
#pragma unroll
        for (int v = 0; v < 4; ++v) {
            C[(long)(crow0 + v) * ldc + col] = (OUT_T)(acc[nf][v] + bv);
        }
    }
}

// ---------------- fused S = softmax((q/8) k^T) -> bf16: grid (24 bh, 4 m-tiles) ----------------
__global__ __launch_bounds__(256) void qk_softmax(
    const bf16_t* __restrict__ qkv,   // [B,256,2304]
    bf16_t* __restrict__ probs)       // [24,256,256] bf16
{
    const int bh = blockIdx.x;
    const int b = bh / 12, h = bh % 12;
    const int m0 = blockIdx.y * 64;
    const bf16_t* qbase = qkv + (long)b * 589824 + h * 64;
    const bf16_t* kbase = qkv + (long)b * 589824 + 768 + h * 64;

    __shared__ __align__(16) bf16_t Qs[64][72];
    __shared__ __align__(16) bf16_t Ks[256][72];

    const int t = threadIdx.x;
#pragma unroll
    for (int c = 0; c < 2; ++c) {
        const int chunk = c * 256 + t;
        const int row = chunk >> 3, off = (chunk & 7) * 8;
        *reinterpret_cast<uint4*>(&Qs[row][off]) =
            *reinterpret_cast<const uint4*>(qbase + (long)(m0 + row) * 2304 + off);
    }
#pragma unroll
    for (int c = 0; c < 8; ++c) {
        const int chunk = c * 256 + t;
        const int row = chunk >> 3, off = (chunk & 7) * 8;
        *reinterpret_cast<uint4*>(&Ks[row][off]) =
            *reinterpret_cast<const uint4*>(kbase + (long)row * 2304 + off);
    }
    __syncthreads();

    const int lane = t & 63, wave = t >> 6;
    f32x4 acc[16] = {};
#pragma unroll
    for (int ks = 0; ks < 64; ks += 32) {
        bf16x8 af = *reinterpret_cast<const bf16x8*>(&Qs[wave * 16 + (lane & 15)][(lane >> 4) * 8 + ks]);
#pragma unroll
        for (int nf = 0; nf < 16; ++nf) {
            bf16x8 bfr = *reinterpret_cast<const bf16x8*>(&Ks[nf * 16 + (lane & 15)][(lane >> 4) * 8 + ks]);
            acc[nf] = __builtin_amdgcn_mfma_f32_16x16x32_bf16(af, bfr, acc[nf], 0, 0, 0);
        }
    }

    float inv[4];
#pragma unroll
    for (int v = 0; v < 4; ++v) {
        float mm = -1e30f;
#pragma unroll
        for (int nf = 0; nf < 16; ++nf) { acc[nf][v] *= 0.125f; mm = fmaxf(mm, acc[nf][v]); }
#pragma unroll
        for (int o = 1; o < 16; o <<= 1) mm = fmaxf(mm, __shfl_xor(mm, o));
        float s = 0.0f;
#pragma unroll
        for (int nf = 0; nf < 16; ++nf) { float e = __expf(acc[nf][v] - mm); acc[nf][v] = e; s += e; }
#pragma unroll
        for (int o = 1; o < 16; o <<= 1) s += __shfl_xor(s, o);
        inv[v] = 1.0f / s;
    }

    bf16_t* prow = probs + ((long)bh * 256 + m0 + wave * 16 + (lane >> 4) * 4) * 256 + (lane & 15);
#pragma unroll
    for (int nf = 0; nf < 16; ++nf) {
#pragma unroll
        for (int v = 0; v < 4; ++v) {
            prow[(long)v * 256 + nf * 16] = (bf16_t)(acc[nf][v] * inv[v]);
        }
    }
}

// ---------------- fused: oh[b,i,c] = sum_j attn * (v + d) ----------------
// Plain (cacheable) d loads: no within-pass reuse, but L3 retains ~half of d across
// graph replays (measured: FETCH 217MB of 402MB on r12/r13) — NT hint forfeited that.
__global__ __launch_bounds__(256) void attnd_kernel(
    const bf16_t* __restrict__ attn,  // [24,256,256] bf16 probs
    const bf16_t* __restrict__ qkv,   // [B,256,2304]
    const float* __restrict__ d,      // [B,256,256,768]
    bf16_t* __restrict__ oh)          // [B,256,768]
{
    const int bi = blockIdx.x;
    const int b  = bi >> 8;
    const int i  = bi & 255;
    const int cc = blockIdx.y;
    const int t  = threadIdx.x;
    const int lane = t & 63, wave = t >> 6;

    __shared__ float attn_s[4 * 257];
    __shared__ f32x4 partial[3][64];

#pragma unroll
    for (int q = 0; q < 4; ++q) {
        attn_s[q * 257 + t] = (float)attn[(((long)(b * 12 + cc * 4 + q)) * 256 + i) * 256 + t];
    }
    __syncthreads();

    const int c0 = cc * 256 + lane * 4;
    const float* arow = attn_s + (lane >> 4) * 257;
    const int jb = wave * 64;
    const f32x4* dp = reinterpret_cast<const f32x4*>(d + (long)bi * 196608 + (long)jb * 768 + c0);
    const bf16_t* vp = qkv + (long)b * 589824 + (long)jb * 2304 + 1536 + c0;

    f32x4 acc = {};
#pragma unroll 8
    for (int jj = 0; jj < 64; ++jj) {
        f32x4 dv = dp[(long)jj * 192];
        bf16x4 vv = *reinterpret_cast<const bf16x4*>(vp + (long)jj * 2304);
        float a = arow[jb + jj];
        acc[0] = fmaf(a, dv[0] + (float)vv[0], acc[0]);
        acc[1] = fmaf(a, dv[1] + (float)vv[1], acc[1]);
        acc[2] = fmaf(a, dv[2] + (float)vv[2], acc[2]);
        acc[3] = fmaf(a, dv[3] + (float)vv[3], acc[3]);
    }

    if (wave) partial[wave - 1][lane] = acc;
    __syncthreads();
    if (wave == 0) {
        acc += partial[0][lane] + partial[1][lane] + partial[2][lane];
        bf16x4 o = { (bf16_t)acc[0], (bf16_t)acc[1], (bf16_t)acc[2], (bf16_t)acc[3] };
        *reinterpret_cast<bf16x4*>(oh + (long)bi * 768 + c0) = o;
    }
}

// ---------------- launch ----------------
extern "C" void kernel_launch(void* const* d_in, const int* in_sizes, int n_in,
                              void* d_out, int out_size, void* d_ws, size_t ws_size,
                              hipStream_t stream) {
    const float* x      = (const float*)d_in[0];   // [2,256,768]
    const float* d      = (const float*)d_in[1];   // [2,256,256,768]
    const float* w_qkv  = (const float*)d_in[2];   // [2304,768]
    const float* w_proj = (const float*)d_in[3];   // [768,768]
    const float* b_proj = (const float*)d_in[4];   // [768]
    float* out = (float*)d_out;                    // [2,256,768]

    char* ws = (char*)d_ws;
    bf16_t* qkvb  = (bf16_t*)(ws);                 //  512x2304 bf16
    bf16_t* probs = (bf16_t*)(ws + 2359296);       //  24x256x256 bf16
    bf16_t* oh    = (bf16_t*)(ws + 5505024);       //  512x768 bf16

    // 1. qkv = x @ w_qkv^T -> bf16 [512,2304]  (288 tiles, XCD-remapped)
    gemm_bt<float, float, bf16_t, false><<<288, 256, 0, stream>>>(
        x, w_qkv, qkvb, nullptr, 768, 768, 768, 2304);

    // 2. probs = softmax((q/8) k^T) -> bf16 [24,256,256]
    qk_softmax<<<dim3(24, 4), 256, 0, stream>>>(qkvb, probs);

    // 3. oh = attn @ (v + d_pair) -> bf16 [512,768]
    attnd_kernel<<<dim3(512, 3), 256, 0, stream>>>(probs, qkvb, d, oh);

    // 4. out = oh @ w_proj^T + b_proj -> fp32  (96 tiles, XCD-remapped)
    gemm_bt<bf16_t, float, float, true><<<96, 256, 0, stream>>>(
        oh, w_proj, out, b_proj, 768, 768, 768, 768);
}